// Round 1
// baseline (620.757 us; speedup 1.0000x reference)
//
#include <hip/hip_runtime.h>
#include <stdint.h>

#define D_IN   2048
#define D_OUT  512

typedef __bf16 bf16;
typedef bf16  bf16x8 __attribute__((ext_vector_type(8)));
typedef float f32x4  __attribute__((ext_vector_type(4)));

#define GLP(p)  (const __attribute__((address_space(1))) void*)(p)
#define LDSP(p) (__attribute__((address_space(3))) void*)(p)

// ---------------- degree count ----------------
__global__ void k_count(const int* __restrict__ dstv, int* __restrict__ cnt, int E) {
    int e = blockIdx.x * blockDim.x + threadIdx.x;
    if (e < E) atomicAdd(&cnt[dstv[e]], 1);
}

// dis[i] = rsqrt(deg) with deg = in-edges + 1 (self loop)
__global__ void k_dis(const int* __restrict__ cnt, float* __restrict__ dis, int n) {
    int i = blockIdx.x * blockDim.x + threadIdx.x;
    if (i < n) dis[i] = rsqrtf((float)(cnt[i] + 1));
}

// ---------------- exclusive prefix sum (single block, wave-scan) ----------------
__global__ __launch_bounds__(1024) void k_scan(const int* __restrict__ cnt,
                                               int* __restrict__ offs, int n) {
    __shared__ int wsum[16];
    __shared__ int wbase[16];
    __shared__ int carry;
    const int tid = threadIdx.x;
    const int lane = tid & 63, wv = tid >> 6;
    if (tid == 0) carry = 0;
    __syncthreads();
    for (int start = 0; start < n; start += 1024) {
        int i = start + tid;
        int v = (i < n) ? cnt[i] : 0;
        int x = v;
        #pragma unroll
        for (int d = 1; d < 64; d <<= 1) {
            int y = __shfl_up(x, d);
            if (lane >= d) x += y;
        }
        if (lane == 63) wsum[wv] = x;
        __syncthreads();
        if (tid < 16) {
            int s = 0;
            for (int j = 0; j < tid; ++j) s += wsum[j];
            wbase[tid] = s;
        }
        __syncthreads();
        if (i < n) offs[i] = carry + wbase[wv] + x - v;
        int total = wbase[15] + wsum[15];
        __syncthreads();
        if (tid == 0) carry += total;
        // next iteration's first LDS write is ordered by its own barriers
    }
}

// ---------------- CSR fill ----------------
__global__ void k_fill(const int* __restrict__ srcv, const int* __restrict__ dstv,
                       const int* __restrict__ offs, int* __restrict__ cur,
                       int* __restrict__ csr, int E) {
    int e = blockIdx.x * blockDim.x + threadIdx.x;
    if (e < E) {
        int d = dstv[e];
        int p = offs[d] + atomicAdd(&cur[d], 1);
        csr[p] = srcv[e];
    }
}

// ---------------- weight transpose + bf16 cast: wt[n][k] = (bf16)W[k][n] ----------------
__global__ void k_wt(const float* __restrict__ W, uint16_t* __restrict__ wt) {
    __shared__ float t[32][33];
    int kb = blockIdx.x * 32, nb = blockIdx.y * 32;
    int tx = threadIdx.x, ty = threadIdx.y;
    #pragma unroll
    for (int i = 0; i < 32; i += 8)
        t[ty + i][tx] = W[(size_t)(kb + ty + i) * D_OUT + nb + tx];
    __syncthreads();
    bf16* o = (bf16*)wt;
    #pragma unroll
    for (int i = 0; i < 32; i += 8)
        o[(size_t)(nb + ty + i) * D_IN + kb + tx] = (bf16)t[tx][ty + i];
}

// ---------------- GEMM: H[M][512] = X[M][2048] * W, A fp32 -> bf16 in-kernel ----------------
// 128x128 tile, BK=32, 4 waves (2x2), each wave 64x64 via 4x4 frags of 16x16x32.
__global__ __launch_bounds__(256) void k_gemm(const float* __restrict__ X,
                                              const uint16_t* __restrict__ WT,
                                              float* __restrict__ H, int M) {
    __shared__ float    lsA[128 * 32];   // 16 KB, 8 units(16B)/row, swizzled u^(row&7)
    __shared__ uint16_t lsB[128 * 32];   // 8 KB, 4 units/row, swizzled u^((row>>1)&3)
    const int n0 = blockIdx.x * 128;     // N tiles fast -> consecutive blocks share A panel
    const int m0 = blockIdx.y * 128;
    const int tid = threadIdx.x;
    const int w = tid >> 6, lane = tid & 63;
    const int wr = w >> 1, wc = w & 1;
    const int lr = lane & 15, lk = lane >> 4;

    f32x4 acc[4][4];
    #pragma unroll
    for (int m = 0; m < 4; m++)
        #pragma unroll
        for (int n = 0; n < 4; n++) acc[m][n] = (f32x4)(0.0f);

    // staging coords (global source pre-swizzled; LDS dest linear)
    int aRow[4], aCol[4];
    #pragma unroll
    for (int j = 0; j < 4; j++) {
        int c = w * 4 + j;
        int uidx = c * 64 + lane;
        int row = uidx >> 3, u = uidx & 7;
        int us = u ^ (row & 7);
        int grow = m0 + row;
        if (grow >= M) grow = M - 1;     // clamp: garbage staged but never stored
        aRow[j] = grow; aCol[j] = us * 4;
    }
    int bRow[2], bCol[2];
    #pragma unroll
    for (int j = 0; j < 2; j++) {
        int c = w * 2 + j;
        int uidx = c * 64 + lane;
        int row = uidx >> 2, u = uidx & 3;
        int us = u ^ ((row >> 1) & 3);
        bRow[j] = n0 + row; bCol[j] = us * 8;
    }

    for (int k0 = 0; k0 < D_IN; k0 += 32) {
        #pragma unroll
        for (int j = 0; j < 4; j++) {
            const float* gp = X + (size_t)aRow[j] * D_IN + k0 + aCol[j];
            __builtin_amdgcn_global_load_lds(GLP(gp), LDSP(lsA + (w * 4 + j) * 256), 16, 0, 0);
        }
        #pragma unroll
        for (int j = 0; j < 2; j++) {
            const uint16_t* gp = WT + (size_t)bRow[j] * D_IN + k0 + bCol[j];
            __builtin_amdgcn_global_load_lds(GLP(gp), LDSP(lsB + (w * 2 + j) * 512), 16, 0, 0);
        }
        __syncthreads();   // drains vmcnt -> LDS ready

        bf16x8 aF[4], bF[4];
        #pragma unroll
        for (int m = 0; m < 4; m++) {
            int row = wr * 64 + m * 16 + lr;
            const float* base = lsA + row * 32;
            f32x4 a0 = *(const f32x4*)(base + (((2 * lk)    ) ^ (row & 7)) * 4);
            f32x4 a1 = *(const f32x4*)(base + (((2 * lk) + 1) ^ (row & 7)) * 4);
            bf16x8 af;
            af[0] = (bf16)a0[0]; af[1] = (bf16)a0[1]; af[2] = (bf16)a0[2]; af[3] = (bf16)a0[3];
            af[4] = (bf16)a1[0]; af[5] = (bf16)a1[1]; af[6] = (bf16)a1[2]; af[7] = (bf16)a1[3];
            aF[m] = af;
        }
        #pragma unroll
        for (int n = 0; n < 4; n++) {
            int row = wc * 64 + n * 16 + lr;
            bF[n] = *(const bf16x8*)((const bf16*)lsB + row * 32 + (lk ^ ((row >> 1) & 3)) * 8);
        }
        #pragma unroll
        for (int m = 0; m < 4; m++)
            #pragma unroll
            for (int n = 0; n < 4; n++)
                acc[m][n] = __builtin_amdgcn_mfma_f32_16x16x32_bf16(aF[m], bF[n], acc[m][n], 0, 0, 0);
        __syncthreads();   // protect LDS before next stage
    }

    // epilogue: C/D layout col=lane&15, row=(lane>>4)*4+reg  [m89-verified]
    #pragma unroll
    for (int m = 0; m < 4; m++) {
        int rbase = m0 + wr * 64 + m * 16 + lk * 4;
        #pragma unroll
        for (int n = 0; n < 4; n++) {
            int col = n0 + wc * 64 + n * 16 + lr;
            #pragma unroll
            for (int j = 0; j < 4; j++) {
                int row = rbase + j;
                if (row < M) H[(size_t)row * D_OUT + col] = acc[m][n][j];
            }
        }
    }
}

// ---------------- aggregation + bias + log_softmax, one block per node ----------------
__global__ __launch_bounds__(128) void k_agg(const float* __restrict__ h,
                                             const int* __restrict__ csr,
                                             const int* __restrict__ offs,
                                             const int* __restrict__ cnt,
                                             const float* __restrict__ dis,
                                             const float* __restrict__ bias,
                                             float* __restrict__ out) {
    const int i = blockIdx.x;
    const int t = threadIdx.x;            // 128 threads x float4 = 512 cols
    const float di = dis[i];
    f32x4 acc;
    {
        f32x4 hv = ((const f32x4*)(h + (size_t)i * D_OUT))[t];
        acc = hv * (di * di);             // self-loop term
    }
    const int o = offs[i], c = cnt[i];
    for (int e = o; e < o + c; ++e) {
        int s = csr[e];
        float wv = di * dis[s];
        f32x4 hv = ((const f32x4*)(h + (size_t)s * D_OUT))[t];
        acc += hv * wv;
    }
    acc += ((const f32x4*)bias)[t];

    // log-softmax over the 512-wide row
    float mx = fmaxf(fmaxf(acc[0], acc[1]), fmaxf(acc[2], acc[3]));
    #pragma unroll
    for (int d = 1; d < 64; d <<= 1) mx = fmaxf(mx, __shfl_xor(mx, d));
    __shared__ float red[2];
    if ((t & 63) == 0) red[t >> 6] = mx;
    __syncthreads();
    mx = fmaxf(red[0], red[1]);
    __syncthreads();
    float se = expf(acc[0] - mx) + expf(acc[1] - mx) + expf(acc[2] - mx) + expf(acc[3] - mx);
    #pragma unroll
    for (int d = 1; d < 64; d <<= 1) se += __shfl_xor(se, d);
    if ((t & 63) == 0) red[t >> 6] = se;
    __syncthreads();
    float lse = mx + logf(red[0] + red[1]);
    f32x4 o4;
    o4[0] = acc[0] - lse; o4[1] = acc[1] - lse; o4[2] = acc[2] - lse; o4[3] = acc[3] - lse;
    ((f32x4*)(out + (size_t)i * D_OUT))[t] = o4;
}

// ---------------- launch ----------------
extern "C" void kernel_launch(void* const* d_in, const int* in_sizes, int n_in,
                              void* d_out, int out_size, void* d_ws, size_t ws_size,
                              hipStream_t stream) {
    const float* x    = (const float*)d_in[0];
    const int*   ei   = (const int*)d_in[1];
    const float* W    = (const float*)d_in[2];
    const float* bias = (const float*)d_in[3];
    float* out = (float*)d_out;

    const int N = in_sizes[0] / D_IN;     // 50000
    const int E = in_sizes[1] / 2;        // 400000
    const int* srcv = ei;
    const int* dstv = ei + E;

    char* p = (char*)d_ws;
    auto carve = [&](size_t b) { void* r = (void*)p; p += (b + 255) & ~(size_t)255; return r; };
    float*    h    = (float*)carve((size_t)N * D_OUT * sizeof(float));   // 102.4 MB
    uint16_t* wt   = (uint16_t*)carve((size_t)D_OUT * D_IN * 2);         // 2 MB
    int*      cnt  = (int*)carve((size_t)N * 4);
    float*    dis  = (float*)carve((size_t)N * 4);
    int*      offs = (int*)carve((size_t)N * 4);
    int*      cur  = (int*)carve((size_t)N * 4);
    int*      csr  = (int*)carve((size_t)E * 4);

    hipMemsetAsync(cnt, 0, (size_t)N * 4, stream);
    hipMemsetAsync(cur, 0, (size_t)N * 4, stream);

    k_wt<<<dim3(D_IN / 32, D_OUT / 32), dim3(32, 8), 0, stream>>>(W, wt);
    k_count<<<(E + 255) / 256, 256, 0, stream>>>(dstv, cnt, E);
    k_dis<<<(N + 255) / 256, 256, 0, stream>>>(cnt, dis, N);
    k_scan<<<1, 1024, 0, stream>>>(cnt, offs, N);
    k_fill<<<(E + 255) / 256, 256, 0, stream>>>(srcv, dstv, offs, cur, csr, E);

    k_gemm<<<dim3(D_OUT / 128, (N + 127) / 128), 256, 0, stream>>>(x, wt, h, N);

    k_agg<<<N, 128, 0, stream>>>(h, csr, offs, cnt, dis, bias, out);
}

// Round 2
// 438.890 us; speedup vs baseline: 1.4144x; 1.4144x over previous
//
#include <hip/hip_runtime.h>
#include <stdint.h>

#define D_IN   2048
#define D_OUT  512

typedef __bf16 bf16;
typedef bf16     bf16x8 __attribute__((ext_vector_type(8)));
typedef float    f32x4  __attribute__((ext_vector_type(4)));
typedef uint32_t u32x4  __attribute__((ext_vector_type(4)));

#define GLP(p)  (const __attribute__((address_space(1))) void*)(p)
#define LDSP(p) (__attribute__((address_space(3))) void*)(p)

// ---------------- fp32 -> bf16 cast (streaming) ----------------
__global__ __launch_bounds__(256) void k_cast(const float* __restrict__ x,
                                              uint16_t* __restrict__ xb, size_t n8) {
    size_t i = (size_t)blockIdx.x * blockDim.x + threadIdx.x;
    size_t stride = (size_t)gridDim.x * blockDim.x;
    const f32x4* xi = (const f32x4*)x;
    bf16x8* xo = (bf16x8*)xb;
    for (; i < n8; i += stride) {
        f32x4 a = xi[2 * i], b = xi[2 * i + 1];
        bf16x8 o;
        o[0] = (bf16)a[0]; o[1] = (bf16)a[1]; o[2] = (bf16)a[2]; o[3] = (bf16)a[3];
        o[4] = (bf16)b[0]; o[5] = (bf16)b[1]; o[6] = (bf16)b[2]; o[7] = (bf16)b[3];
        xo[i] = o;
    }
}

// ---------------- degree count ----------------
__global__ void k_count(const int* __restrict__ dstv, int* __restrict__ cnt, int E) {
    int e = blockIdx.x * blockDim.x + threadIdx.x;
    if (e < E) atomicAdd(&cnt[dstv[e]], 1);
}

__global__ void k_dis(const int* __restrict__ cnt, float* __restrict__ dis, int n) {
    int i = blockIdx.x * blockDim.x + threadIdx.x;
    if (i < n) dis[i] = rsqrtf((float)(cnt[i] + 1));
}

// ---------------- hierarchical exclusive scan ----------------
__global__ __launch_bounds__(1024) void k_scan1(const int* __restrict__ cnt,
                                                int* __restrict__ offs,
                                                int* __restrict__ bsum, int n) {
    __shared__ int wsum[16], wbase[16];
    const int tid = threadIdx.x, lane = tid & 63, wv = tid >> 6;
    int i = blockIdx.x * 1024 + tid;
    int v = (i < n) ? cnt[i] : 0;
    int x = v;
    #pragma unroll
    for (int d = 1; d < 64; d <<= 1) {
        int y = __shfl_up(x, d);
        if (lane >= d) x += y;
    }
    if (lane == 63) wsum[wv] = x;
    __syncthreads();
    if (tid < 16) {
        int s = 0;
        for (int j = 0; j < tid; ++j) s += wsum[j];
        wbase[tid] = s;
    }
    __syncthreads();
    if (i < n) offs[i] = wbase[wv] + x - v;
    if (tid == 0) bsum[blockIdx.x] = wbase[15] + wsum[15];
}

__global__ void k_scan2(int* __restrict__ bsum, int nb) {
    int t = threadIdx.x;
    if (nb <= 64) {
        int v = (t < nb) ? bsum[t] : 0;
        int x = v;
        #pragma unroll
        for (int d = 1; d < 64; d <<= 1) {
            int y = __shfl_up(x, d);
            if (t >= d) x += y;
        }
        if (t < nb) bsum[t] = x - v;   // exclusive
    } else if (t == 0) {
        int run = 0;
        for (int j = 0; j < nb; ++j) { int v = bsum[j]; bsum[j] = run; run += v; }
    }
}

__global__ void k_scan3(int* __restrict__ offs, const int* __restrict__ bsum, int n) {
    int i = blockIdx.x * blockDim.x + threadIdx.x;
    if (i < n) offs[i] += bsum[i >> 10];
}

// ---------------- CSR fill ----------------
__global__ void k_fill(const int* __restrict__ srcv, const int* __restrict__ dstv,
                       const int* __restrict__ offs, int* __restrict__ cur,
                       int* __restrict__ csr, int E) {
    int e = blockIdx.x * blockDim.x + threadIdx.x;
    if (e < E) {
        int d = dstv[e];
        int p = offs[d] + atomicAdd(&cur[d], 1);
        csr[p] = srcv[e];
    }
}

// ---------------- weight transpose + bf16 cast: wt[n][k] = (bf16)W[k][n] ----------------
__global__ void k_wt(const float* __restrict__ W, uint16_t* __restrict__ wt) {
    __shared__ float t[32][33];
    int kb = blockIdx.x * 32, nb = blockIdx.y * 32;
    int tx = threadIdx.x, ty = threadIdx.y;
    #pragma unroll
    for (int i = 0; i < 32; i += 8)
        t[ty + i][tx] = W[(size_t)(kb + ty + i) * D_OUT + nb + tx];
    __syncthreads();
    bf16* o = (bf16*)wt;
    #pragma unroll
    for (int i = 0; i < 32; i += 8)
        o[(size_t)(nb + ty + i) * D_IN + kb + tx] = (bf16)t[tx][ty + i];
}

// ---------------- GEMM: H[M][512] = Xb[M][2048](bf16) * W  (m97 structure) ----------------
// 128x128 tile, BK=64, 4 waves (2x2), each wave 64x64 via 4x4 frags of 16x16x32.
// LDS rows = 128B = 8x16B units, XOR-swizzle u^(row&7) on BOTH source and read.
__global__ __launch_bounds__(256) void k_gemm(const uint16_t* __restrict__ Xb0,
                                              const uint16_t* __restrict__ Xb1,
                                              const uint16_t* __restrict__ WT,
                                              uint16_t* __restrict__ H, int M, int R0) {
    __shared__ uint16_t lsA[128 * 64];   // 16 KB
    __shared__ uint16_t lsB[128 * 64];   // 16 KB
    // bijective chunked XCD swizzle (m204): same m-panel's 4 n-blocks -> same XCD
    const int nwg = gridDim.x;
    const int b = blockIdx.x;
    const int q = nwg >> 3, r = nwg & 7;
    const int xcd = b & 7, lo = b >> 3;
    const int g = (xcd < r) ? (xcd * (q + 1) + lo) : (r * (q + 1) + (xcd - r) * q + lo);
    const int m0 = (g >> 2) * 128;
    const int n0 = (g & 3) * 128;
    const int tid = threadIdx.x;
    const int w = tid >> 6, lane = tid & 63;
    const int wr = w >> 1, wc = w & 1;
    const int lr = lane & 15, lk = lane >> 4;

    const uint16_t* Abase = (m0 < R0) ? (Xb0 + (size_t)m0 * D_IN)
                                      : (Xb1 + (size_t)(m0 - R0) * D_IN);

    f32x4 acc[4][4];
    #pragma unroll
    for (int m = 0; m < 4; m++)
        #pragma unroll
        for (int n = 0; n < 4; n++) acc[m][n] = (f32x4)(0.0f);

    const uint16_t* aSrc[4];
    const uint16_t* bSrc[4];
    #pragma unroll
    for (int j = 0; j < 4; j++) {
        int c = w * 4 + j;
        int uidx = c * 64 + lane;
        int row = uidx >> 3, u = uidx & 7;
        int lrow = row;
        if (m0 + row >= M) lrow = (M - 1) - m0;   // clamp: valid data staged, stores masked
        aSrc[j] = Abase + (size_t)lrow * D_IN + (u ^ (row & 7)) * 8;
        bSrc[j] = WT + (size_t)(n0 + row) * D_IN + (u ^ (row & 7)) * 8;
    }

    for (int k0 = 0; k0 < D_IN; k0 += 64) {
        #pragma unroll
        for (int j = 0; j < 4; j++)
            __builtin_amdgcn_global_load_lds(GLP(aSrc[j] + k0), LDSP(lsA + (w * 4 + j) * 512), 16, 0, 0);
        #pragma unroll
        for (int j = 0; j < 4; j++)
            __builtin_amdgcn_global_load_lds(GLP(bSrc[j] + k0), LDSP(lsB + (w * 4 + j) * 512), 16, 0, 0);
        __syncthreads();

        #pragma unroll
        for (int kk = 0; kk < 2; kk++) {
            bf16x8 aF[4], bF[4];
            #pragma unroll
            for (int m = 0; m < 4; m++) {
                int row = wr * 64 + m * 16 + lr;
                aF[m] = *(const bf16x8*)(lsA + row * 64 + (((kk * 4 + lk) ^ (row & 7)) * 8));
            }
            #pragma unroll
            for (int n = 0; n < 4; n++) {
                int row = wc * 64 + n * 16 + lr;
                bF[n] = *(const bf16x8*)(lsB + row * 64 + (((kk * 4 + lk) ^ (row & 7)) * 8));
            }
            #pragma unroll
            for (int m = 0; m < 4; m++)
                #pragma unroll
                for (int n = 0; n < 4; n++)
                    acc[m][n] = __builtin_amdgcn_mfma_f32_16x16x32_bf16(aF[m], bF[n], acc[m][n], 0, 0, 0);
        }
        __syncthreads();
    }

    // epilogue: C/D layout col=lane&15, row=(lane>>4)*4+reg; store bf16
    #pragma unroll
    for (int m = 0; m < 4; m++) {
        int rbase = m0 + wr * 64 + m * 16 + lk * 4;
        #pragma unroll
        for (int n = 0; n < 4; n++) {
            int col = n0 + wc * 64 + n * 16 + lr;
            #pragma unroll
            for (int j = 0; j < 4; j++) {
                int row = rbase + j;
                if (row < M) {
                    bf16 t = (bf16)acc[m][n][j];
                    H[(size_t)row * D_OUT + col] = __builtin_bit_cast(uint16_t, t);
                }
            }
        }
    }
}

// ---------------- aggregation + bias + log_softmax, one wave per node ----------------
__global__ __launch_bounds__(256) void k_agg(const uint16_t* __restrict__ h,
                                             const int* __restrict__ csr,
                                             const int* __restrict__ offs,
                                             const int* __restrict__ cnt,
                                             const float* __restrict__ dis,
                                             const float* __restrict__ bias,
                                             float* __restrict__ out, int N) {
    const int wv = threadIdx.x >> 6, lane = threadIdx.x & 63;
    const int i = blockIdx.x * 4 + wv;
    if (i >= N) return;
    const float di = dis[i];
    float acc[8];
    {
        u32x4 v = *(const u32x4*)(h + (size_t)i * D_OUT + lane * 8);
        float s2 = di * di;
        #pragma unroll
        for (int k = 0; k < 4; k++) {
            acc[2 * k]     = __builtin_bit_cast(float, v[k] << 16) * s2;
            acc[2 * k + 1] = __builtin_bit_cast(float, v[k] & 0xffff0000u) * s2;
        }
    }
    const int o = offs[i], c = cnt[i];
    for (int e = o; e < o + c; ++e) {
        int s = csr[e];
        float ws = di * dis[s];
        u32x4 v = *(const u32x4*)(h + (size_t)s * D_OUT + lane * 8);
        #pragma unroll
        for (int k = 0; k < 4; k++) {
            acc[2 * k]     += __builtin_bit_cast(float, v[k] << 16) * ws;
            acc[2 * k + 1] += __builtin_bit_cast(float, v[k] & 0xffff0000u) * ws;
        }
    }
    {
        const f32x4* bp = (const f32x4*)(bias + lane * 8);
        f32x4 b0 = bp[0], b1 = bp[1];
        #pragma unroll
        for (int k = 0; k < 4; k++) { acc[k] += b0[k]; acc[4 + k] += b1[k]; }
    }
    float mx = acc[0];
    #pragma unroll
    for (int k = 1; k < 8; k++) mx = fmaxf(mx, acc[k]);
    #pragma unroll
    for (int d = 1; d < 64; d <<= 1) mx = fmaxf(mx, __shfl_xor(mx, d));
    float se = 0.f;
    #pragma unroll
    for (int k = 0; k < 8; k++) se += expf(acc[k] - mx);
    #pragma unroll
    for (int d = 1; d < 64; d <<= 1) se += __shfl_xor(se, d);
    float lse = mx + logf(se);
    f32x4 o0, o1;
    #pragma unroll
    for (int k = 0; k < 4; k++) { o0[k] = acc[k] - lse; o1[k] = acc[4 + k] - lse; }
    f32x4* op = (f32x4*)(out + (size_t)i * D_OUT + lane * 8);
    op[0] = o0; op[1] = o1;
}

// ---------------- launch ----------------
extern "C" void kernel_launch(void* const* d_in, const int* in_sizes, int n_in,
                              void* d_out, int out_size, void* d_ws, size_t ws_size,
                              hipStream_t stream) {
    const float* x    = (const float*)d_in[0];
    const int*   ei   = (const int*)d_in[1];
    const float* W    = (const float*)d_in[2];
    const float* bias = (const float*)d_in[3];
    float* out = (float*)d_out;

    const int N = in_sizes[0] / D_IN;     // 50000
    const int E = in_sizes[1] / 2;        // 400000
    const int* srcv = ei;
    const int* dstv = ei + E;

    // rows of bf16 X that fit in d_out (used as scratch until k_agg), 128-aligned
    int R0 = (int)(((size_t)N * D_OUT * 4 / (D_IN * 2)) / 128) * 128;  // 24960
    if (R0 > N) R0 = N;
    const int R1 = N - R0;

    char* p = (char*)d_ws;
    auto carve = [&](size_t b) { void* r = (void*)p; p += (b + 255) & ~(size_t)255; return r; };
    uint16_t* xb1  = (uint16_t*)carve((size_t)R1 * D_IN * 2);            // ~102.6 MB
    uint16_t* h    = (uint16_t*)carve((size_t)N * D_OUT * 2);            // 51.2 MB
    uint16_t* wt   = (uint16_t*)carve((size_t)D_OUT * D_IN * 2);         // 2 MB
    int*      cnt  = (int*)carve((size_t)N * 4);
    float*    dis  = (float*)carve((size_t)N * 4);
    int*      offs = (int*)carve((size_t)N * 4);
    int*      cur  = (int*)carve((size_t)N * 4);
    int*      csr  = (int*)carve((size_t)E * 4);
    int*      bsum = (int*)carve(1024 * 4);

    uint16_t* xb0 = (uint16_t*)d_out;     // d_out as scratch for first R0 rows

    hipMemsetAsync(cnt, 0, (size_t)N * 4, stream);
    hipMemsetAsync(cur, 0, (size_t)N * 4, stream);

    k_cast<<<2048, 256, 0, stream>>>(x, xb0, (size_t)R0 * D_IN / 8);
    k_cast<<<2048, 256, 0, stream>>>(x + (size_t)R0 * D_IN, xb1, (size_t)R1 * D_IN / 8);
    k_wt<<<dim3(D_IN / 32, D_OUT / 32), dim3(32, 8), 0, stream>>>(W, wt);

    k_count<<<(E + 255) / 256, 256, 0, stream>>>(dstv, cnt, E);
    k_dis<<<(N + 255) / 256, 256, 0, stream>>>(cnt, dis, N);
    const int nb = (N + 1023) / 1024;
    k_scan1<<<nb, 1024, 0, stream>>>(cnt, offs, bsum, N);
    k_scan2<<<1, 64, 0, stream>>>(bsum, nb);
    k_scan3<<<(N + 255) / 256, 256, 0, stream>>>(offs, bsum, N);
    k_fill<<<(E + 255) / 256, 256, 0, stream>>>(srcv, dstv, offs, cur, csr, E);

    k_gemm<<<((N + 127) / 128) * 4, 256, 0, stream>>>(xb0, xb1, wt, h, N, R0);

    k_agg<<<(N + 3) / 4, 256, 0, stream>>>(h, csr, offs, cnt, dis, bias, out, N);
}

// Round 3
// 342.601 us; speedup vs baseline: 1.8119x; 1.2811x over previous
//
#include <hip/hip_runtime.h>
#include <stdint.h>

#define D_IN   2048
#define D_OUT  512

typedef __bf16 bf16;
typedef bf16     bf16x8 __attribute__((ext_vector_type(8)));
typedef float    f32x4  __attribute__((ext_vector_type(4)));
typedef uint32_t u32x4  __attribute__((ext_vector_type(4)));

#define GLP(p)  (const __attribute__((address_space(1))) void*)(p)
#define LDSP(p) (__attribute__((address_space(3))) void*)(p)

// ---------------- degree count ----------------
__global__ void k_count(const int* __restrict__ dstv, int* __restrict__ cnt, int E) {
    int e = blockIdx.x * blockDim.x + threadIdx.x;
    if (e < E) atomicAdd(&cnt[dstv[e]], 1);
}

__global__ void k_dis(const int* __restrict__ cnt, float* __restrict__ dis, int n) {
    int i = blockIdx.x * blockDim.x + threadIdx.x;
    if (i < n) dis[i] = rsqrtf((float)(cnt[i] + 1));
}

// ---------------- hierarchical exclusive scan ----------------
__global__ __launch_bounds__(1024) void k_scan1(const int* __restrict__ cnt,
                                                int* __restrict__ offs,
                                                int* __restrict__ bsum, int n) {
    __shared__ int wsum[16], wbase[16];
    const int tid = threadIdx.x, lane = tid & 63, wv = tid >> 6;
    int i = blockIdx.x * 1024 + tid;
    int v = (i < n) ? cnt[i] : 0;
    int x = v;
    #pragma unroll
    for (int d = 1; d < 64; d <<= 1) {
        int y = __shfl_up(x, d);
        if (lane >= d) x += y;
    }
    if (lane == 63) wsum[wv] = x;
    __syncthreads();
    if (tid < 16) {
        int s = 0;
        for (int j = 0; j < tid; ++j) s += wsum[j];
        wbase[tid] = s;
    }
    __syncthreads();
    if (i < n) offs[i] = wbase[wv] + x - v;
    if (tid == 0) bsum[blockIdx.x] = wbase[15] + wsum[15];
}

__global__ void k_scan2(int* __restrict__ bsum, int nb) {
    int t = threadIdx.x;
    if (nb <= 64) {
        int v = (t < nb) ? bsum[t] : 0;
        int x = v;
        #pragma unroll
        for (int d = 1; d < 64; d <<= 1) {
            int y = __shfl_up(x, d);
            if (t >= d) x += y;
        }
        if (t < nb) bsum[t] = x - v;   // exclusive
    } else if (t == 0) {
        int run = 0;
        for (int j = 0; j < nb; ++j) { int v = bsum[j]; bsum[j] = run; run += v; }
    }
}

__global__ void k_scan3(int* __restrict__ offs, const int* __restrict__ bsum, int n) {
    int i = blockIdx.x * blockDim.x + threadIdx.x;
    if (i < n) offs[i] += bsum[i >> 10];
}

// ---------------- CSR fill ----------------
__global__ void k_fill(const int* __restrict__ srcv, const int* __restrict__ dstv,
                       const int* __restrict__ offs, int* __restrict__ cur,
                       int* __restrict__ csr, int E) {
    int e = blockIdx.x * blockDim.x + threadIdx.x;
    if (e < E) {
        int d = dstv[e];
        int p = offs[d] + atomicAdd(&cur[d], 1);
        csr[p] = srcv[e];
    }
}

// ---------------- weight transpose + bf16 cast: wt[n][k] = (bf16)W[k][n] ----------------
__global__ void k_wt(const float* __restrict__ W, uint16_t* __restrict__ wt) {
    __shared__ float t[32][33];
    int kb = blockIdx.x * 32, nb = blockIdx.y * 32;
    int tx = threadIdx.x, ty = threadIdx.y;
    #pragma unroll
    for (int i = 0; i < 32; i += 8)
        t[ty + i][tx] = W[(size_t)(kb + ty + i) * D_OUT + nb + tx];
    __syncthreads();
    bf16* o = (bf16*)wt;
    #pragma unroll
    for (int i = 0; i < 32; i += 8)
        o[(size_t)(nb + ty + i) * D_IN + kb + tx] = (bf16)t[tx][ty + i];
}

// ---------------- fused GEMM: H[M][512] = (bf16)X[M][2048](fp32) * W ----------------
// 128x128 tile, BK=64, 4 waves (2x2), 4x4 frags of 16x16x32.
// A staged fp32 as two 32-col halves; each half has 128B rows = 8x16B units,
// XOR-swizzle u^(row&7) applied to BOTH pre-swizzled global source and LDS read.
// B staged bf16 (64 cols = 128B rows), same involution.
__global__ __launch_bounds__(256) void k_gemm(const float* __restrict__ X,
                                              const uint16_t* __restrict__ WT,
                                              uint16_t* __restrict__ H, int M) {
    __shared__ float    lsA[2][128 * 32];  // 32 KB
    __shared__ uint16_t lsB[128 * 64];     // 16 KB
    // bijective chunked XCD swizzle: one m-panel's 4 n-blocks -> same XCD
    const int nwg = gridDim.x;
    const int b = blockIdx.x;
    const int q = nwg >> 3, r = nwg & 7;
    const int xcd = b & 7, lo = b >> 3;
    const int g = (xcd < r) ? (xcd * (q + 1) + lo) : (r * (q + 1) + (xcd - r) * q + lo);
    const int m0 = (g >> 2) * 128;
    const int n0 = (g & 3) * 128;
    const int tid = threadIdx.x;
    const int w = tid >> 6, lane = tid & 63;
    const int wr = w >> 1, wc = w & 1;
    const int lr = lane & 15, lk = lane >> 4;

    f32x4 acc[4][4];
    #pragma unroll
    for (int m = 0; m < 4; m++)
        #pragma unroll
        for (int n = 0; n < 4; n++) acc[m][n] = (f32x4)(0.0f);

    const float* aSrc[2][4];
    const uint16_t* bSrc[4];
    #pragma unroll
    for (int j = 0; j < 4; j++) {
        int c = w * 4 + j;
        int uidx = c * 64 + lane;
        int row = uidx >> 3, u = uidx & 7;
        int lrow = row;
        if (m0 + row >= M) lrow = (M - 1) - m0;   // clamp: valid data staged, stores masked
        const float* rbase = X + (size_t)(m0 + lrow) * D_IN;
        #pragma unroll
        for (int h = 0; h < 2; h++)
            aSrc[h][j] = rbase + h * 32 + (u ^ (row & 7)) * 4;
        bSrc[j] = WT + (size_t)(n0 + row) * D_IN + (u ^ (row & 7)) * 8;
    }

    for (int k0 = 0; k0 < D_IN; k0 += 64) {
        #pragma unroll
        for (int h = 0; h < 2; h++)
            #pragma unroll
            for (int j = 0; j < 4; j++)
                __builtin_amdgcn_global_load_lds(GLP(aSrc[h][j] + k0),
                                                 LDSP(lsA[h] + (w * 4 + j) * 256), 16, 0, 0);
        #pragma unroll
        for (int j = 0; j < 4; j++)
            __builtin_amdgcn_global_load_lds(GLP(bSrc[j] + k0),
                                             LDSP(lsB + (w * 4 + j) * 512), 16, 0, 0);
        __syncthreads();

        #pragma unroll
        for (int kk = 0; kk < 2; kk++) {
            bf16x8 aF[4], bF[4];
            #pragma unroll
            for (int m = 0; m < 4; m++) {
                int row = wr * 64 + m * 16 + lr;
                const float* base = lsA[kk] + row * 32;
                f32x4 a0 = *(const f32x4*)(base + (((2 * lk)    ) ^ (row & 7)) * 4);
                f32x4 a1 = *(const f32x4*)(base + (((2 * lk) + 1) ^ (row & 7)) * 4);
                bf16x8 af;
                af[0] = (bf16)a0[0]; af[1] = (bf16)a0[1]; af[2] = (bf16)a0[2]; af[3] = (bf16)a0[3];
                af[4] = (bf16)a1[0]; af[5] = (bf16)a1[1]; af[6] = (bf16)a1[2]; af[7] = (bf16)a1[3];
                aF[m] = af;
            }
            #pragma unroll
            for (int n = 0; n < 4; n++) {
                int row = wc * 64 + n * 16 + lr;
                bF[n] = *(const bf16x8*)((const bf16*)lsB + row * 64 + (((kk * 4 + lk) ^ (row & 7)) * 8));
            }
            #pragma unroll
            for (int m = 0; m < 4; m++)
                #pragma unroll
                for (int n = 0; n < 4; n++)
                    acc[m][n] = __builtin_amdgcn_mfma_f32_16x16x32_bf16(aF[m], bF[n], acc[m][n], 0, 0, 0);
        }
        __syncthreads();
    }

    // epilogue: C/D layout col=lane&15, row=(lane>>4)*4+reg; store bf16
    #pragma unroll
    for (int m = 0; m < 4; m++) {
        int rbase = m0 + wr * 64 + m * 16 + lk * 4;
        #pragma unroll
        for (int n = 0; n < 4; n++) {
            int col = n0 + wc * 64 + n * 16 + lr;
            #pragma unroll
            for (int j = 0; j < 4; j++) {
                int row = rbase + j;
                if (row < M) {
                    bf16 t = (bf16)acc[m][n][j];
                    H[(size_t)row * D_OUT + col] = __builtin_bit_cast(uint16_t, t);
                }
            }
        }
    }
}

// ---------------- aggregation + bias + log_softmax, one wave per node ----------------
__global__ __launch_bounds__(256) void k_agg(const uint16_t* __restrict__ h,
                                             const int* __restrict__ csr,
                                             const int* __restrict__ offs,
                                             const int* __restrict__ cnt,
                                             const float* __restrict__ dis,
                                             const float* __restrict__ bias,
                                             float* __restrict__ out, int N) {
    const int wv = threadIdx.x >> 6, lane = threadIdx.x & 63;
    const int i = blockIdx.x * 4 + wv;
    if (i >= N) return;
    const float di = dis[i];
    float acc[8];
    {
        u32x4 v = *(const u32x4*)(h + (size_t)i * D_OUT + lane * 8);
        float s2 = di * di;
        #pragma unroll
        for (int k = 0; k < 4; k++) {
            acc[2 * k]     = __builtin_bit_cast(float, v[k] << 16) * s2;
            acc[2 * k + 1] = __builtin_bit_cast(float, v[k] & 0xffff0000u) * s2;
        }
    }
    const int o = offs[i], c = cnt[i];
    for (int e = o; e < o + c; ++e) {
        int s = csr[e];
        float ws = di * dis[s];
        u32x4 v = *(const u32x4*)(h + (size_t)s * D_OUT + lane * 8);
        #pragma unroll
        for (int k = 0; k < 4; k++) {
            acc[2 * k]     += __builtin_bit_cast(float, v[k] << 16) * ws;
            acc[2 * k + 1] += __builtin_bit_cast(float, v[k] & 0xffff0000u) * ws;
        }
    }
    {
        const f32x4* bp = (const f32x4*)(bias + lane * 8);
        f32x4 b0 = bp[0], b1 = bp[1];
        #pragma unroll
        for (int k = 0; k < 4; k++) { acc[k] += b0[k]; acc[4 + k] += b1[k]; }
    }
    float mx = acc[0];
    #pragma unroll
    for (int k = 1; k < 8; k++) mx = fmaxf(mx, acc[k]);
    #pragma unroll
    for (int d = 1; d < 64; d <<= 1) mx = fmaxf(mx, __shfl_xor(mx, d));
    float se = 0.f;
    #pragma unroll
    for (int k = 0; k < 8; k++) se += expf(acc[k] - mx);
    #pragma unroll
    for (int d = 1; d < 64; d <<= 1) se += __shfl_xor(se, d);
    float lse = mx + logf(se);
    f32x4 o0, o1;
    #pragma unroll
    for (int k = 0; k < 4; k++) { o0[k] = acc[k] - lse; o1[k] = acc[4 + k] - lse; }
    f32x4* op = (f32x4*)(out + (size_t)i * D_OUT + lane * 8);
    op[0] = o0; op[1] = o1;
}

// ---------------- launch ----------------
extern "C" void kernel_launch(void* const* d_in, const int* in_sizes, int n_in,
                              void* d_out, int out_size, void* d_ws, size_t ws_size,
                              hipStream_t stream) {
    const float* x    = (const float*)d_in[0];
    const int*   ei   = (const int*)d_in[1];
    const float* W    = (const float*)d_in[2];
    const float* bias = (const float*)d_in[3];
    float* out = (float*)d_out;

    const int N = in_sizes[0] / D_IN;     // 50000
    const int E = in_sizes[1] / 2;        // 400000
    const int* srcv = ei;
    const int* dstv = ei + E;

    char* p = (char*)d_ws;
    auto carve = [&](size_t b) { void* r = (void*)p; p += (b + 255) & ~(size_t)255; return r; };
    uint16_t* h    = (uint16_t*)carve((size_t)N * D_OUT * 2);            // 51.2 MB
    uint16_t* wt   = (uint16_t*)carve((size_t)D_OUT * D_IN * 2);         // 2 MB
    int*      cnt  = (int*)carve((size_t)N * 4);                         // cnt+cur adjacent
    int*      cur  = (int*)carve((size_t)N * 4);
    float*    dis  = (float*)carve((size_t)N * 4);
    int*      offs = (int*)carve((size_t)N * 4);
    int*      csr  = (int*)carve((size_t)E * 4);
    int*      bsum = (int*)carve(1024 * 4);

    hipMemsetAsync(cnt, 0, ((size_t)N * 4 + 255 & ~(size_t)255) + (size_t)N * 4, stream);

    k_wt<<<dim3(D_IN / 32, D_OUT / 32), dim3(32, 8), 0, stream>>>(W, wt);
    k_count<<<(E + 255) / 256, 256, 0, stream>>>(dstv, cnt, E);
    k_dis<<<(N + 255) / 256, 256, 0, stream>>>(cnt, dis, N);
    const int nb = (N + 1023) / 1024;
    k_scan1<<<nb, 1024, 0, stream>>>(cnt, offs, bsum, N);
    k_scan2<<<1, 64, 0, stream>>>(bsum, nb);
    k_scan3<<<(N + 255) / 256, 256, 0, stream>>>(offs, bsum, N);
    k_fill<<<(E + 255) / 256, 256, 0, stream>>>(srcv, dstv, offs, cur, csr, E);

    k_gemm<<<((N + 127) / 128) * 4, 256, 0, stream>>>(x, wt, h, N);

    k_agg<<<(N + 3) / 4, 256, 0, stream>>>(h, csr, offs, cnt, dis, bias, out, N);
}